// Round 5
// baseline (309.205 us; speedup 1.0000x reference)
//
#include <hip/hip_runtime.h>

#define NB 8
#define NS 2048
#define ND 256
#define NH 4
#define NHD 64
#define ND2 512
#define NM (NB * NS)
#define PITCH 72  // padded LDS row pitch for Pl (bf16 elems)

typedef __attribute__((ext_vector_type(8))) short          bf16x8;
typedef __attribute__((ext_vector_type(4))) float          f32x4;
typedef unsigned short ushort_t;
typedef unsigned int   uint_t;

#define MFMA16(a, b, c) __builtin_amdgcn_mfma_f32_16x16x32_bf16(a, b, c, 0, 0, 0)

// pack two fp32 -> packed bf16 pair (a -> low16, b -> high16), round-nearest
// via +0x8000 then v_perm byte-select of the two high halves (1 VALU op).
static __device__ inline uint_t pack2bf(float a, float b) {
    union { float f; uint_t u; } x, y; x.f = a; y.f = b;
    return __builtin_amdgcn_perm(y.u + 0x8000u, x.u + 0x8000u, 0x07060302u);
}

// async global->LDS DMA, 16B per lane; l must be wave-uniform, lane i's data
// lands at l + i*16.
static __device__ inline void gl_lds(const ushort_t* g, ushort_t* l) {
    __builtin_amdgcn_global_load_lds(
        (const __attribute__((address_space(1))) void*)g,
        (__attribute__((address_space(3))) void*)l, 16, 0, 0);
}

// ---------------------------------------------------------------------------
// fp32 -> bf16 convert for desc / source (grid.y selects buffer)
// ---------------------------------------------------------------------------
__global__ __launch_bounds__(256) void convert_acts(
    const float* __restrict__ d, const float* __restrict__ s,
    ushort_t* __restrict__ db, ushort_t* __restrict__ sb)
{
    const float* src = blockIdx.y ? s : d;
    ushort_t* dst    = blockIdx.y ? sb : db;
    const size_t i = ((size_t)blockIdx.x * 256 + threadIdx.x) * 4;
    float4 v = *(const float4*)(src + i);
    uint2 pv;
    pv.x = pack2bf(v.x, v.y);
    pv.y = pack2bf(v.z, v.w);
    *(uint2*)(dst + i) = pv;
}

// ---------------------------------------------------------------------------
// fp32 W[K][N] -> bf16 WT[N][K] for all 6 weights (grid.y selects weight)
// ---------------------------------------------------------------------------
__global__ __launch_bounds__(256) void transpose_w(
    const float* q, const float* k, const float* v, const float* o,
    const float* m0, const float* m1,
    ushort_t* qt, ushort_t* kt, ushort_t* vt, ushort_t* ot,
    ushort_t* m0t, ushort_t* m1t)
{
    const float* src; ushort_t* dst; int K, N;
    switch (blockIdx.y) {
        case 0: src = q;  dst = qt;  K = 256; N = 256; break;
        case 1: src = k;  dst = kt;  K = 256; N = 256; break;
        case 2: src = v;  dst = vt;  K = 256; N = 256; break;
        case 3: src = o;  dst = ot;  K = 256; N = 256; break;
        case 4: src = m0; dst = m0t; K = 512; N = 512; break;
        default: src = m1; dst = m1t; K = 512; N = 256; break;
    }
    const int idx = blockIdx.x * 256 + threadIdx.x;
    if (idx >= N * (K >> 3)) return;
    const int ksh = (K == 512) ? 6 : 5;
    const int n  = idx >> ksh;
    const int kc = (idx & ((1 << ksh) - 1)) << 3;
    float f[8];
#pragma unroll
    for (int j = 0; j < 8; j++) f[j] = src[(size_t)(kc + j) * N + n];
    uint4 pk;
    pk.x = pack2bf(f[0], f[1]);
    pk.y = pack2bf(f[2], f[3]);
    pk.z = pack2bf(f[4], f[5]);
    pk.w = pack2bf(f[6], f[7]);
    *(uint4*)(dst + (size_t)n * K + kc) = pk;
}

// ---------------------------------------------------------------------------
// bf16 MFMA GEMM, 128x128 tile, BK=64, 256 thr = 4 waves (wave tile 64x64,
// 4x4 of 16x16x32 MFMA). Staging via global_load_lds into swizzled unpadded
// LDS [kgrp(8)][row(128)][8] -> fragment b128 reads are lane-contiguous
// (2-way bank alias = free), no ds_writes, no VGPR roundtrip.
// Act split column-wise at K0 (BK=64 never straddles). WT pre-transposed.
// MODE 0: swapped ops, bf16 head-major [b][h][s][64]          (q/k proj)
// MODE 1: swapped ops, bf16 row-major [tok][N]                (o-proj)
// MODE 2: swapped ops, bf16 row-major + BN + ReLU             (MLP0)
// MODE 3: swapped ops, fp32 row-major                         (MLP1 -> out)
// MODE 4: natural ops, bf16 head-transposed [b][h][dv][s]     (v proj)
// ---------------------------------------------------------------------------
template <int MODE>
__global__ __launch_bounds__(256) void gemm_mfma(
    const ushort_t* __restrict__ A0, const ushort_t* __restrict__ A1, int K0,
    const ushort_t* __restrict__ WT, const float* __restrict__ bias,
    const float* __restrict__ bng, const float* __restrict__ bnb,
    const float* __restrict__ bnm, const float* __restrict__ bnv,
    void* __restrict__ outp, int N, int K)
{
    __shared__ ushort_t Al[128 * 64];   // swizzled [kgrp][row][8]
    __shared__ ushort_t Wl[128 * 64];

    const int t  = threadIdx.x;
    const int w  = t >> 6;
    const int lq = t & 15;
    const int lg = (t & 63) >> 4;
    const int n0   = blockIdx.x << 7;
    const int row0 = blockIdx.y << 7;
    const int wm = (w & 1) << 6;
    const int wn = (w >> 1) << 6;

    f32x4 acc[4][4];
#pragma unroll
    for (int mt = 0; mt < 4; mt++)
#pragma unroll
        for (int nt = 0; nt < 4; nt++) acc[mt][nt] = (f32x4){0.f, 0.f, 0.f, 0.f};

    for (int kt = 0; kt < K; kt += 64) {
        const bool first = (kt < K0);
        const ushort_t* Asrc = first ? A0 : A1;
        const int lda = first ? K0 : (K - K0);
        const int kb  = first ? kt : (kt - K0);
        __syncthreads();
        // DMA staging: chunk p = r*256 + t -> row = p&127, kgrp = p>>7;
        // wave-uniform LDS base = (r*256 + w*64) chunks.
#pragma unroll
        for (int r = 0; r < 4; r++) {
            const int p   = r * 256 + t;
            const int row = p & 127;
            const int kg  = p >> 7;
            const int lb  = (r * 256 + w * 64) * 8;
            gl_lds(Asrc + (size_t)(row0 + row) * lda + kb + kg * 8, &Al[lb]);
            gl_lds(WT + (size_t)(n0 + row) * K + kt + kg * 8, &Wl[lb]);
        }
        __syncthreads();
#pragma unroll
        for (int kc = 0; kc < 2; kc++) {
            bf16x8 af[4], wf[4];
#pragma unroll
            for (int mt = 0; mt < 4; mt++)
                af[mt] = *(const bf16x8*)&Al[(((kc * 4 + lg) << 7) + wm + mt * 16 + lq) * 8];
#pragma unroll
            for (int nt = 0; nt < 4; nt++)
                wf[nt] = *(const bf16x8*)&Wl[(((kc * 4 + lg) << 7) + wn + nt * 16 + lq) * 8];
#pragma unroll
            for (int mt = 0; mt < 4; mt++)
#pragma unroll
                for (int nt = 0; nt < 4; nt++) {
                    if (MODE == 4)
                        acc[mt][nt] = MFMA16(af[mt], wf[nt], acc[mt][nt]);
                    else
                        acc[mt][nt] = MFMA16(wf[nt], af[mt], acc[mt][nt]);
                }
        }
    }

    if (MODE == 4) {
        // natural: lane holds 4 consecutive tokens at channel dv
        ushort_t* vout = (ushort_t*)outp;
#pragma unroll
        for (int nt = 0; nt < 4; nt++) {
            const int dvg = n0 + wn + nt * 16 + lq;
            const int h  = dvg >> 6;
            const int dv = dvg & 63;
            const float bs = bias[dvg];
#pragma unroll
            for (int mt = 0; mt < 4; mt++) {
                const int tok0 = row0 + wm + mt * 16 + lg * 4;
                const int b = tok0 >> 11;
                const int s = tok0 & 2047;
                uint2 pv;
                pv.x = pack2bf(acc[mt][nt][0] + bs, acc[mt][nt][1] + bs);
                pv.y = pack2bf(acc[mt][nt][2] + bs, acc[mt][nt][3] + bs);
                *(uint2*)(vout + ((size_t)(b * NH + h) * NHD + dv) * NS + s) = pv;
            }
        }
    } else {
        // swapped: lane holds 4 consecutive channels at one token
#pragma unroll
        for (int nt = 0; nt < 4; nt++) {
            const int nb = n0 + wn + nt * 16 + lg * 4;
            f32x4 bs = *(const f32x4*)(bias + nb);
            f32x4 g4, b4, m4, v4;
            if (MODE == 2) {
                g4 = *(const f32x4*)(bng + nb);
                b4 = *(const f32x4*)(bnb + nb);
                m4 = *(const f32x4*)(bnm + nb);
                v4 = *(const f32x4*)(bnv + nb);
            }
#pragma unroll
            for (int mt = 0; mt < 4; mt++) {
                const int tok = row0 + wm + mt * 16 + lq;
                float r[4];
#pragma unroll
                for (int j = 0; j < 4; j++) {
                    float x = acc[mt][nt][j] + bs[j];
                    if (MODE == 2) {
                        x = (x - m4[j]) * rsqrtf(v4[j] + 1e-5f) * g4[j] + b4[j];
                        x = fmaxf(x, 0.0f);
                    }
                    r[j] = x;
                }
                if (MODE == 3) {
                    f32x4 o4 = {r[0], r[1], r[2], r[3]};
                    *(f32x4*)((float*)outp + (size_t)tok * N + nb) = o4;
                } else if (MODE == 0) {
                    const int b = tok >> 11;
                    const int s = tok & 2047;
                    const int h = nb >> 6;
                    const int d = nb & 63;
                    uint2 pv;
                    pv.x = pack2bf(r[0], r[1]);
                    pv.y = pack2bf(r[2], r[3]);
                    *(uint2*)((ushort_t*)outp + ((size_t)(b * NH + h) * NS + s) * NHD + d) = pv;
                } else {
                    uint2 pv;
                    pv.x = pack2bf(r[0], r[1]);
                    pv.y = pack2bf(r[2], r[3]);
                    *(uint2*)((ushort_t*)outp + (size_t)tok * N + nb) = pv;
                }
            }
        }
    }
}

// ---------------------------------------------------------------------------
// MFMA flash cross-attention v2 (bf16 in/out). Grid (S/128, H, B), 4 waves,
// wave owns 32 q rows (2 tiles). No running max (scores bounded: softmax
// without max-subtract is exact), scale folded with log2e into one mul,
// exp2, perm-packed P, K-fragments register-cached per chunk, per-(wave,qt)
// Pl regions, K/V staged by global_load_lds into swizzled unpadded LDS.
// ---------------------------------------------------------------------------
__global__ __launch_bounds__(256) void attn_mfma(
    const ushort_t* __restrict__ qbf, const ushort_t* __restrict__ kbf,
    const ushort_t* __restrict__ vtbf, const int* __restrict__ mask,
    ushort_t* __restrict__ ctxb)
{
    __shared__ ushort_t Kl[64 * 64];        // swizzled [kgrp(8)][row(64)][8]
    __shared__ ushort_t Vl[64 * 64];
    __shared__ ushort_t Pl[8][16 * PITCH];  // [w*2+qt][q(16)][key(64) padded]

    const int t  = threadIdx.x;
    const int w  = t >> 6;
    const int lq = t & 15;
    const int lg = (t & 63) >> 4;
    const int qb = blockIdx.x;
    const int h  = blockIdx.y;
    const int b  = blockIdx.z;
    const int bh = b * NH + h;
    const float c1 = 0.18033688f;  // 0.125 * log2(e)

    const ushort_t* qh = qbf + (size_t)bh * NS * NHD;
    const ushort_t* kh = kbf + (size_t)bh * NS * NHD;
    const ushort_t* vh = vtbf + (size_t)bh * NHD * NS;
    const int* mrow = mask + b * NS;
    const int qrow0 = qb * 128 + w * 32;

    // Q fragments (B-operand): lane holds Q[q=lq][d = dh*32 + lg*8 ..+8]
    bf16x8 qf[2][2];
#pragma unroll
    for (int qt = 0; qt < 2; qt++)
#pragma unroll
        for (int dh = 0; dh < 2; dh++)
            qf[qt][dh] = *(const bf16x8*)(qh + (size_t)(qrow0 + qt * 16 + lq) * NHD
                                          + dh * 32 + lg * 8);

    f32x4 o[2][4];
#pragma unroll
    for (int qt = 0; qt < 2; qt++)
#pragma unroll
        for (int dt = 0; dt < 4; dt++) o[qt][dt] = (f32x4){0.f, 0.f, 0.f, 0.f};
    float l_run[2] = {0.0f, 0.0f};

    for (int key0 = 0; key0 < NS; key0 += 64) {
        __syncthreads();  // prior chunk's LDS reads done before DMA overwrite
        // stage K[key][d] and V^T[dv][key] swizzled: p = r*256+t,
        // row = p&63, kgrp = p>>6, wave-uniform base = (r*256 + w*64)
#pragma unroll
        for (int r = 0; r < 2; r++) {
            const int p   = r * 256 + t;
            const int row = p & 63;
            const int kg  = p >> 6;
            const int lb  = (r * 256 + w * 64) * 8;
            gl_lds(kh + (size_t)(key0 + row) * NHD + kg * 8, &Kl[lb]);
            gl_lds(vh + (size_t)row * NS + key0 + kg * 8, &Vl[lb]);
        }
        __syncthreads();

        // K fragments (A-operand) cached in regs: used by both q-tiles
        bf16x8 ka[4][2];
#pragma unroll
        for (int kt = 0; kt < 4; kt++)
#pragma unroll
            for (int kk = 0; kk < 2; kk++)
                ka[kt][kk] = *(const bf16x8*)
                    &Kl[(((kk * 4 + lg) << 6) + kt * 16 + lq) * 8];

        // mask for this lane's key rows: key = key0 + kt*16 + lg*4 + r
        int4 mv[4];
#pragma unroll
        for (int kt = 0; kt < 4; kt++)
            mv[kt] = *(const int4*)(mrow + key0 + kt * 16 + lg * 4);

#pragma unroll
        for (int qt = 0; qt < 2; qt++) {
            // S^T[key][q] = K·Q^T  (C-layout: col = q = lq)
            f32x4 st[4];
#pragma unroll
            for (int kt = 0; kt < 4; kt++) {
                f32x4 a = (f32x4){0.f, 0.f, 0.f, 0.f};
                a = MFMA16(ka[kt][0], qf[qt][0], a);
                a = MFMA16(ka[kt][1], qf[qt][1], a);
                st[kt] = a;
            }
            // p = exp2(s*c1) (no max-subtract); mask -> -1e9; pack bf16
            float ls = 0.0f;
#pragma unroll
            for (int kt = 0; kt < 4; kt++) {
                float pr[4];
#pragma unroll
                for (int r = 0; r < 4; r++) {
                    float x = st[kt][r] * c1;
                    x = ((&mv[kt].x)[r] == 0) ? -1e9f : x;
                    const float p = exp2f(x);
                    ls += p;
                    pr[r] = p;
                }
                uint2 pv;
                pv.x = pack2bf(pr[0], pr[1]);
                pv.y = pack2bf(pr[2], pr[3]);
                *(uint2*)&Pl[w * 2 + qt][lq * PITCH + kt * 16 + lg * 4] = pv;
            }
            ls += __shfl_xor(ls, 16);
            ls += __shfl_xor(ls, 32);
            l_run[qt] += ls;
        }

        // P B-fragments (per qt region — no overwrite hazard)
        bf16x8 pf[2][2];
#pragma unroll
        for (int qt = 0; qt < 2; qt++)
#pragma unroll
            for (int kh2 = 0; kh2 < 2; kh2++)
                pf[qt][kh2] = *(const bf16x8*)
                    &Pl[w * 2 + qt][lq * PITCH + kh2 * 32 + lg * 8];

        // ctx^T[dv][q] += V^T·P  (vf shared across both q-tiles)
#pragma unroll
        for (int dt = 0; dt < 4; dt++)
#pragma unroll
            for (int kh2 = 0; kh2 < 2; kh2++) {
                bf16x8 vf = *(const bf16x8*)
                    &Vl[(((kh2 * 4 + lg) << 6) + dt * 16 + lq) * 8];
#pragma unroll
                for (int qt = 0; qt < 2; qt++)
                    o[qt][dt] = MFMA16(vf, pf[qt][kh2], o[qt][dt]);
            }
    }

    // epilogue: divide by l, write bf16 ctx[token][256]
#pragma unroll
    for (int qt = 0; qt < 2; qt++) {
        const float li = 1.0f / l_run[qt];
        const int tok = b * NS + qrow0 + qt * 16 + lq;
#pragma unroll
        for (int dt = 0; dt < 4; dt++) {
            uint2 pv;
            pv.x = pack2bf(o[qt][dt][0] * li, o[qt][dt][1] * li);
            pv.y = pack2bf(o[qt][dt][2] * li, o[qt][dt][3] * li);
            *(uint2*)(ctxb + (size_t)tok * ND + h * NHD + dt * 16 + lg * 4) = pv;
        }
    }
}

extern "C" void kernel_launch(void* const* d_in, const int* in_sizes, int n_in,
                              void* d_out, int out_size, void* d_ws, size_t ws_size,
                              hipStream_t stream)
{
    (void)in_sizes; (void)n_in; (void)out_size; (void)ws_size;
    const float* desc = (const float*)d_in[0];
    const float* srcp = (const float*)d_in[1];
    const int*   mask = (const int*)d_in[2];
    const float* q_w  = (const float*)d_in[3];
    const float* q_b  = (const float*)d_in[4];
    const float* k_w  = (const float*)d_in[5];
    const float* k_b  = (const float*)d_in[6];
    const float* v_w  = (const float*)d_in[7];
    const float* v_b  = (const float*)d_in[8];
    const float* o_w  = (const float*)d_in[9];
    const float* o_b  = (const float*)d_in[10];
    const float* m0_w = (const float*)d_in[11];
    const float* m0_b = (const float*)d_in[12];
    const float* bng  = (const float*)d_in[13];
    const float* bnb  = (const float*)d_in[14];
    const float* bnm  = (const float*)d_in[15];
    const float* bnv  = (const float*)d_in[16];
    const float* m1_w = (const float*)d_in[17];
    const float* m1_b = (const float*)d_in[18];
    float* out = (float*)d_out;

    const size_t ASZ = (size_t)NM * ND;  // 4,194,304 elems
    ushort_t* desc_bf = (ushort_t*)d_ws;
    ushort_t* src_bf  = desc_bf + ASZ;
    ushort_t* qbf     = desc_bf + 2 * ASZ;
    ushort_t* kbf     = desc_bf + 3 * ASZ;
    ushort_t* vtbf    = desc_bf + 4 * ASZ;
    ushort_t* qwT     = desc_bf + 5 * ASZ;
    ushort_t* kwT     = qwT + 65536;
    ushort_t* vwT     = kwT + 65536;
    ushort_t* owT     = vwT + 65536;
    ushort_t* m0T     = owT + 65536;
    ushort_t* m1T     = m0T + 262144;
    ushort_t* ctx_bf  = src_bf;   // src dead after V-proj
    ushort_t* abuf    = qbf;      // q dead after attention
    ushort_t* hbuf    = kbf;      // k+v dead after attention

    const dim3 blk(256);
    const dim3 gq(2, 128);   // N=256 GEMMs, 128x128 tiles
    const dim3 gh(4, 128);   // N=512 GEMM

    convert_acts<<<dim3(ASZ / 1024, 2), blk, 0, stream>>>(desc, srcp, desc_bf, src_bf);
    transpose_w<<<dim3(128, 6), blk, 0, stream>>>(q_w, k_w, v_w, o_w, m0_w, m1_w,
                                                  qwT, kwT, vwT, owT, m0T, m1T);
    gemm_mfma<0><<<gq, blk, 0, stream>>>(desc_bf, desc_bf, ND, qwT, q_b,
                                         bng, bnb, bnm, bnv, qbf, ND, ND);
    gemm_mfma<0><<<gq, blk, 0, stream>>>(src_bf, src_bf, ND, kwT, k_b,
                                         bng, bnb, bnm, bnv, kbf, ND, ND);
    gemm_mfma<4><<<gq, blk, 0, stream>>>(src_bf, src_bf, ND, vwT, v_b,
                                         bng, bnb, bnm, bnv, vtbf, ND, ND);
    attn_mfma<<<dim3(NS / 128, NH, NB), blk, 0, stream>>>(qbf, kbf, vtbf, mask, ctx_bf);
    gemm_mfma<1><<<gq, blk, 0, stream>>>(ctx_bf, ctx_bf, ND, owT, o_b,
                                         bng, bnb, bnm, bnv, abuf, ND, ND);
    gemm_mfma<2><<<gh, blk, 0, stream>>>(desc_bf, abuf, ND, m0T, m0_b,
                                         bng, bnb, bnm, bnv, hbuf, ND2, ND2);
    gemm_mfma<3><<<gq, blk, 0, stream>>>(hbuf, hbuf, ND2, m1T, m1_b,
                                         bng, bnb, bnm, bnv, out, ND, ND2);
}